// Round 1
// baseline (4453.905 us; speedup 1.0000x reference)
//
#include <hip/hip_runtime.h>
#include <hip/hip_bf16.h>
#include <math.h>

#define BATCH 512
#define MAXL 128
#define HID 512
#define H3 1536

typedef __bf16 bf16x8 __attribute__((ext_vector_type(8)));
typedef __bf16 bf16x4 __attribute__((ext_vector_type(4)));
typedef float f32x4 __attribute__((ext_vector_type(4)));

// ---------------- prefix scan of lengths -> starts ----------------
__global__ __launch_bounds__(BATCH) void scan_kernel(const int* __restrict__ len,
                                                     int* __restrict__ starts) {
    __shared__ int buf[BATCH];
    int tid = threadIdx.x;
    int myLen = len[tid];
    buf[tid] = myLen;
    __syncthreads();
    for (int off = 1; off < BATCH; off <<= 1) {
        int v = (tid >= off) ? buf[tid - off] : 0;
        __syncthreads();
        buf[tid] += v;
        __syncthreads();
    }
    starts[tid] = buf[tid] - myLen;   // exclusive scan
}

// ---------------- h0 = segment_max(h); init state + zero sums ----------------
__global__ __launch_bounds__(HID) void init_kernel(const float* __restrict__ h,
                                                   const int* __restrict__ len,
                                                   const int* __restrict__ starts,
                                                   float* __restrict__ hf,      // buffer0 [2][B][H]
                                                   __bf16* __restrict__ hb,     // buffer0 [2][B][H]
                                                   float* __restrict__ sums) {  // [2][B][H]
    int b = blockIdx.x, j = threadIdx.x;
    int s = starts[b], L = len[b];
    float m = -3.4e38f;
    for (int t = 0; t < L; ++t) m = fmaxf(m, h[(size_t)(s + t) * HID + j]);
    size_t i0 = ((size_t)0 * BATCH + b) * HID + j;
    size_t i1 = ((size_t)1 * BATCH + b) * HID + j;
    hf[i0] = m; hf[i1] = m;
    hb[i0] = (__bf16)m; hb[i1] = (__bf16)m;
    sums[i0] = 0.f; sums[i1] = 0.f;
}

// ---------------- message = relu(h + bias) -> bf16 ----------------
__global__ void msg_kernel(const float* __restrict__ h, const float* __restrict__ bias,
                           __bf16* __restrict__ msg, long total4) {
    for (long i = (long)blockIdx.x * blockDim.x + threadIdx.x; i < total4;
         i += (long)gridDim.x * blockDim.x) {
        float4 v = ((const float4*)h)[i];
        int c4 = (int)(i & (HID / 4 - 1));
        float4 bb = ((const float4*)bias)[c4];
        bf16x4 o;
        o[0] = (__bf16)fmaxf(v.x + bb.x, 0.f);
        o[1] = (__bf16)fmaxf(v.y + bb.y, 0.f);
        o[2] = (__bf16)fmaxf(v.z + bb.z, 0.f);
        o[3] = (__bf16)fmaxf(v.w + bb.w, 0.f);
        ((bf16x4*)msg)[i] = o;
    }
}

// ---------------- fp32 -> bf16 weight convert ----------------
__global__ void conv_kernel(const float* __restrict__ src, __bf16* __restrict__ dst, int n4) {
    int i = blockIdx.x * blockDim.x + threadIdx.x;
    if (i < n4) {
        float4 v = ((const float4*)src)[i];
        bf16x4 o;
        o[0] = (__bf16)v.x; o[1] = (__bf16)v.y; o[2] = (__bf16)v.z; o[3] = (__bf16)v.w;
        ((bf16x4*)dst)[i] = o;
    }
}

// ---------------- gx = msg @ w_ih^T  (NT GEMM, bf16 out, no bias) ----------------
// grid: (12, ceil(N/128), 2dirs), block 256 (4 waves, 2x2 of 64x64 wave tiles)
__global__ __launch_bounds__(256) void gx_gemm(const __bf16* __restrict__ msg,
                                               const __bf16* __restrict__ wih,  // [2][1536][512]
                                               __bf16* __restrict__ gx,         // [2][N][1536]
                                               int N) {
    int dir = blockIdx.z;
    int wid = threadIdx.x >> 6, lane = threadIdx.x & 63;
    int r0 = blockIdx.y * 128 + (wid >> 1) * 64;
    int c0 = blockIdx.x * 128 + (wid & 1) * 64;
    int lrow = lane & 15, lk = (lane >> 4) * 8;
    const __bf16* wB = wih + (size_t)dir * H3 * HID;
    f32x4 acc[4][4] = {};
    for (int ks = 0; ks < HID; ks += 32) {
        bf16x8 a[4], b[4];
#pragma unroll
        for (int i = 0; i < 4; ++i) {
            int row = r0 + i * 16 + lrow; if (row >= N) row = N - 1;
            a[i] = *(const bf16x8*)(msg + (size_t)row * HID + ks + lk);
            b[i] = *(const bf16x8*)(wB + (size_t)(c0 + i * 16 + lrow) * HID + ks + lk);
        }
#pragma unroll
        for (int i = 0; i < 4; ++i)
#pragma unroll
            for (int j = 0; j < 4; ++j)
                acc[i][j] = __builtin_amdgcn_mfma_f32_16x16x32_bf16(a[i], b[j], acc[i][j], 0, 0, 0);
    }
    __bf16* gOut = gx + (size_t)dir * N * H3;
#pragma unroll
    for (int i = 0; i < 4; ++i)
#pragma unroll
        for (int j = 0; j < 4; ++j) {
            int col = c0 + j * 16 + (lane & 15);
#pragma unroll
            for (int reg = 0; reg < 4; ++reg) {
                int row = r0 + i * 16 + (lane >> 4) * 4 + reg;
                if (row < N) gOut[(size_t)row * H3 + col] = (__bf16)acc[i][j][reg];
            }
        }
}

// ---------------- one GRU step, both directions fused ----------------
// grid: (8, 8, 2dirs), block 256 = 4 waves; wave tile 32 rows x 32 cols, all 3 gates
__global__ __launch_bounds__(256) void step_kernel(
    int stepIdx,
    const __bf16* __restrict__ hb_cur, __bf16* __restrict__ hb_nxt,   // [2][B][H]
    const float* __restrict__ hf_cur, float* __restrict__ hf_nxt,     // [2][B][H]
    const __bf16* __restrict__ whh,                                   // [2][1536][512]
    const __bf16* __restrict__ gx,                                    // [2][N][1536]
    const float* __restrict__ b_ih_f, const float* __restrict__ b_hh_f,
    const float* __restrict__ b_ih_b, const float* __restrict__ b_hh_b,
    const int* __restrict__ len, const int* __restrict__ starts,
    float* __restrict__ sums, int N) {
    int dir = blockIdx.z;
    int t = dir ? (MAXL - 1 - stepIdx) : stepIdx;
    int wid = threadIdx.x >> 6, lane = threadIdx.x & 63;
    int r0 = blockIdx.y * 64 + (wid >> 1) * 32;
    int c0 = blockIdx.x * 64 + (wid & 1) * 32;
    int lrow = lane & 15, lk = (lane >> 4) * 8;

    const __bf16* hA = hb_cur + (size_t)dir * BATCH * HID;
    const __bf16* wB = whh + (size_t)dir * H3 * HID;

    f32x4 acc[3][2][2] = {};
    for (int ks = 0; ks < HID; ks += 32) {
        bf16x8 a0 = *(const bf16x8*)(hA + (size_t)(r0 + lrow) * HID + ks + lk);
        bf16x8 a1 = *(const bf16x8*)(hA + (size_t)(r0 + 16 + lrow) * HID + ks + lk);
#pragma unroll
        for (int g = 0; g < 3; ++g) {
            bf16x8 b0 = *(const bf16x8*)(wB + (size_t)(g * HID + c0 + lrow) * HID + ks + lk);
            bf16x8 b1 = *(const bf16x8*)(wB + (size_t)(g * HID + c0 + 16 + lrow) * HID + ks + lk);
            acc[g][0][0] = __builtin_amdgcn_mfma_f32_16x16x32_bf16(a0, b0, acc[g][0][0], 0, 0, 0);
            acc[g][0][1] = __builtin_amdgcn_mfma_f32_16x16x32_bf16(a0, b1, acc[g][0][1], 0, 0, 0);
            acc[g][1][0] = __builtin_amdgcn_mfma_f32_16x16x32_bf16(a1, b0, acc[g][1][0], 0, 0, 0);
            acc[g][1][1] = __builtin_amdgcn_mfma_f32_16x16x32_bf16(a1, b1, acc[g][1][1], 0, 0, 0);
        }
    }

    const float* bih = dir ? b_ih_b : b_ih_f;
    const float* bhh = dir ? b_hh_b : b_hh_f;
    int colBase = lane & 15, rowBase = (lane >> 4) * 4;
#pragma unroll
    for (int fi = 0; fi < 2; ++fi)
#pragma unroll
        for (int fj = 0; fj < 2; ++fj) {
            int col = c0 + fj * 16 + colBase;
            float bihr = bih[col], bihz = bih[HID + col], bihn = bih[2 * HID + col];
            float bhhr = bhh[col], bhhz = bhh[HID + col], bhhn = bhh[2 * HID + col];
#pragma unroll
            for (int reg = 0; reg < 4; ++reg) {
                int row = r0 + fi * 16 + rowBase + reg;
                int L = len[row];
                bool real = (t < L);
                float gxr = 0.f, gxz = 0.f, gxn = 0.f;
                if (real) {
                    size_t nidx = ((size_t)dir * N + starts[row] + t) * H3;
                    gxr = (float)gx[nidx + col];
                    gxz = (float)gx[nidx + HID + col];
                    gxn = (float)gx[nidx + 2 * HID + col];
                }
                float ghr = acc[0][fi][fj][reg] + bhhr;
                float ghz = acc[1][fi][fj][reg] + bhhz;
                float ghn = acc[2][fi][fj][reg] + bhhn;
                float rg = 1.f / (1.f + expf(-(gxr + bihr + ghr)));
                float zg = 1.f / (1.f + expf(-(gxz + bihz + ghz)));
                float ng = tanhf(gxn + bihn + rg * ghn);
                size_t hidx = ((size_t)dir * BATCH + row) * HID + col;
                float hold = hf_cur[hidx];
                float hn = (1.f - zg) * ng + zg * hold;
                hf_nxt[hidx] = hn;
                hb_nxt[hidx] = (__bf16)hn;
                if (real) sums[hidx] += hn;
            }
        }
}

// ---------------- finalize: out[b, dir*H+col] = sums / len ----------------
__global__ void fin_kernel(const float* __restrict__ sums, const int* __restrict__ len,
                           float* __restrict__ out) {
    int idx = blockIdx.x * blockDim.x + threadIdx.x;
    if (idx >= BATCH * 2 * HID) return;
    int b = idx >> 10, j = idx & 1023;
    int dir = j >> 9, col = j & 511;
    out[idx] = sums[((size_t)dir * BATCH + b) * HID + col] / (float)len[b];
}

extern "C" void kernel_launch(void* const* d_in, const int* in_sizes, int n_in,
                              void* d_out, int out_size, void* d_ws, size_t ws_size,
                              hipStream_t stream) {
    const float* h      = (const float*)d_in[0];
    const int*   lens   = (const int*)d_in[1];
    const float* bias   = (const float*)d_in[2];
    const float* w_ih_f = (const float*)d_in[3];
    const float* w_hh_f = (const float*)d_in[4];
    const float* b_ih_f = (const float*)d_in[5];
    const float* b_hh_f = (const float*)d_in[6];
    const float* w_ih_b = (const float*)d_in[7];
    const float* w_hh_b = (const float*)d_in[8];
    const float* b_ih_b = (const float*)d_in[9];
    const float* b_hh_b = (const float*)d_in[10];
    float* out = (float*)d_out;
    const int N = in_sizes[0] / HID;

    // workspace layout
    char* p = (char*)d_ws;
    size_t off = 0;
    int* starts = (int*)(p + off);          off += 4096;  // 512*4 padded
    float* sums = (float*)(p + off);        off += (size_t)2 * BATCH * HID * 4;
    float* hf   = (float*)(p + off);        off += (size_t)2 * 2 * BATCH * HID * 4;
    __bf16* hb  = (__bf16*)(p + off);       off += (size_t)2 * 2 * BATCH * HID * 2;
    __bf16* wih = (__bf16*)(p + off);       off += (size_t)2 * H3 * HID * 2;
    __bf16* whh = (__bf16*)(p + off);       off += (size_t)2 * H3 * HID * 2;
    __bf16* msg = (__bf16*)(p + off);       off += (size_t)N * HID * 2;
    __bf16* gx  = (__bf16*)(p + off);       off += (size_t)2 * N * H3 * 2;
    if (off > ws_size) return;  // interpretable failure: output stays zero

    scan_kernel<<<1, BATCH, 0, stream>>>(lens, starts);
    init_kernel<<<BATCH, HID, 0, stream>>>(h, lens, starts, hf, hb, sums);

    long total4 = (long)N * HID / 4;
    int msgBlocks = (int)((total4 + 255) / 256); if (msgBlocks > 2048) msgBlocks = 2048;
    msg_kernel<<<msgBlocks, 256, 0, stream>>>(h, bias, msg, total4);

    int n4 = H3 * HID / 4;
    int cb = (n4 + 255) / 256;
    conv_kernel<<<cb, 256, 0, stream>>>(w_ih_f, wih, n4);
    conv_kernel<<<cb, 256, 0, stream>>>(w_ih_b, wih + (size_t)H3 * HID, n4);
    conv_kernel<<<cb, 256, 0, stream>>>(w_hh_f, whh, n4);
    conv_kernel<<<cb, 256, 0, stream>>>(w_hh_b, whh + (size_t)H3 * HID, n4);

    gx_gemm<<<dim3(12, (N + 127) / 128, 2), 256, 0, stream>>>(msg, wih, gx, N);

    float* hf0 = hf;               float* hf1 = hf + (size_t)2 * BATCH * HID;
    __bf16* hb0 = hb;              __bf16* hb1 = hb + (size_t)2 * BATCH * HID;
    for (int s = 0; s < MAXL; ++s) {
        const float* hfc = (s & 1) ? hf1 : hf0;  float* hfn = (s & 1) ? hf0 : hf1;
        const __bf16* hbc = (s & 1) ? hb1 : hb0; __bf16* hbn = (s & 1) ? hb0 : hb1;
        step_kernel<<<dim3(8, 8, 2), 256, 0, stream>>>(
            s, hbc, hbn, hfc, hfn, whh, gx,
            b_ih_f, b_hh_f, b_ih_b, b_hh_b, lens, starts, sums, N);
    }

    fin_kernel<<<2048, 256, 0, stream>>>(sums, lens, out);
}